// Round 15
// baseline (478.284 us; speedup 1.0000x reference)
//
#include <hip/hip_runtime.h>
#include <math.h>

#define EPSI 1e-5f

typedef float f32x2 __attribute__((ext_vector_type(2)));

// ---------------- workspace layout (floats) ----------------
#define P_D1 2048                    // 128*83*83 = 881792
#define P_D2 (P_D1 + 128*83*83)
#define P_D3 (P_D2 + 128*28*28)
#define P_D4 (P_D3 + 128*10*10)
#define P_D5 (P_D4 + 128*4*4)
#define P_SCORE (P_D5 + 128*2*2)     // 4*64*256*256 = 16777216 floats
#define P_D  P_SCORE                 // d (4,32,248,248) = 7.87M floats, aliases score head
#define P_TAB (P_SCORE + 8388608)    // 17^3 x 32 MLP table in dead tail of score region

__device__ __forceinline__ float rfl(float x) {
  return __builtin_bit_cast(float, __builtin_amdgcn_readfirstlane(__builtin_bit_cast(int, x)));
}

struct PrepArgs { const float* p[39]; };

// ---------------- prep (in-LDS, per block) + 17^3 -> 32 MLP lookup table ----------------
__global__ __launch_bounds__(256) void k_table(PrepArgs a, float* __restrict__ P,
                                               float* __restrict__ T) {
  __shared__ float Pl[1568];
  int t = threadIdx.x;
  {
    const float *w1=a.p[1],*b1=a.p[2],*w2=a.p[3],*b2=a.p[4],*g1=a.p[5],*bb1=a.p[6],*m1=a.p[7],*v1=a.p[8];
    const float *w3=a.p[9],*b3=a.p[10],*w4=a.p[11],*b4=a.p[12],*g2=a.p[13],*bb2=a.p[14],*m2=a.p[15],*v2=a.p[16];
    for (int i=t;i<96;i+=256){ int o=i/3; float s=g1[o]/sqrtf(v1[o]+EPSI); Pl[i]=w1[i]*w2[o]*s; }
    for (int o=t;o<32;o+=256){ float s=g1[o]/sqrtf(v1[o]+EPSI); Pl[96+o]=(b1[o]*w2[o]+b2[o]-m1[o])*s+bb1[o]; }
    for (int i=t;i<1024;i+=256){ int o2=i/32; float s=g2[o2]/sqrtf(v2[o2]+EPSI); Pl[128+i]=w3[i]*w4[o2]*s; }
    for (int o=t;o<32;o+=256){ float s=g2[o]/sqrtf(v2[o]+EPSI); Pl[1152+o]=(b3[o]*w4[o]+b4[o]-m2[o])*s+bb2[o]; }
    const float *iag=a.p[21],*iab=a.p[22],*iam=a.p[23],*iav=a.p[24],*iabias=a.p[20];
    for (int c=t;c<32;c+=256){ float s=iag[c]/sqrtf(iav[c]+EPSI); Pl[1184+c]=s; Pl[1216+c]=(iabias[0]-iam[c])*s+iab[c]; }
    const float *ibg=a.p[27],*ibb=a.p[28],*ibm=a.p[29],*ibv=a.p[30],*ibbias=a.p[26];
    for (int c=t;c<32;c+=256){ float s=ibg[c]/sqrtf(ibv[c]+EPSI); Pl[1248+c]=s; Pl[1280+c]=(ibbias[0]-ibm[c])*s+ibb[c]; }
    const float *f1g=a.p[31],*f1b=a.p[32],*f1m=a.p[33],*f1v=a.p[34];
    for (int c=t;c<64;c+=256){ float s=f1g[c]/sqrtf(f1v[c]+EPSI); Pl[1312+c]=s; Pl[1376+c]=f1b[c]-f1m[c]*s; }
    const float *f2g=a.p[35],*f2b=a.p[36],*f2m=a.p[37],*f2v=a.p[38];
    for (int c=t;c<64;c+=256){ float s=f2g[c]/sqrtf(f2v[c]+EPSI); Pl[1440+c]=s; Pl[1504+c]=f2b[c]-f2m[c]*s; }
  }
  __syncthreads();
  if (blockIdx.x == 0) {
    for (int i = t; i < 1568; i += 256) P[i] = Pl[i];
  }
  int idx = blockIdx.x*256 + t;
  if (idx >= 4913) return;
  int m0 = idx/289; int rem = idx - m0*289; int m1 = rem/17; int m2 = rem - m1*17;
  float md0 = (float)m0*0.0625f, md1 = (float)m1*0.0625f, md2 = (float)m2*0.0625f;
  const float* A1 = Pl;           const float* C1 = Pl + 96;
  const float* A2 = Pl + 128;     const float* C2 = Pl + 1152;
  float h[32];
  #pragma unroll
  for (int o = 0; o < 32; o++) {
    float v = C1[o] + A1[o*3]*md0 + A1[o*3+1]*md1 + A1[o*3+2]*md2;
    h[o] = (v >= 0.f) ? v : 0.01f*v;
  }
  float* tp = T + (size_t)idx*32;
  #pragma unroll
  for (int o2 = 0; o2 < 32; o2++) {
    float acc = C2[o2];
    #pragma unroll
    for (int o = 0; o < 32; o++) acc += A2[o2*32+o]*h[o];
    tp[o2] = (acc >= 0.f) ? acc : 0.01f*acc;
  }
}

// ---------------- quantize + mode-pool(11,1,1) via separable column-histograms + table ----------
__global__ __launch_bounds__(256) void k_mode_mlp(const float* __restrict__ x,
                                                 const float* __restrict__ T,
                                                 float* __restrict__ dout) {
  __shared__ int qs[3*676];          // 8.1 KB
  __shared__ unsigned CH[3*1326];    // 15.9 KB; plane w: w*1326 + ch*442 + cx*17 + oy
  int lx = threadIdx.x, ly = threadIdx.y;
  int tid = ly*16 + lx;
  int tx0 = blockIdx.x*16, ty0 = blockIdx.y*16;
  int b = blockIdx.z;
  for (int k = tid; k < 3*676; k += 256) {
    int cch = k/676; int rem = k - cch*676; int r = rem/26; int cc = rem - r*26;
    int gy = ty0 + r - 1, gx = tx0 + cc - 1;
    int q = 0;
    if ((unsigned)gy < 256u && (unsigned)gx < 256u) {
      float v = x[((size_t)(b*3+cch)*256 + gy)*256 + gx];
      q = (int)rintf(v*255.0f/16.0f);
      q = q < 0 ? 0 : (q > 16 ? 16 : q);
    }
    qs[k] = q;
  }
  __syncthreads();

  if (tid < 156) {
    int half = tid & 1; int rem = tid >> 1;
    int cx = rem % 26; int ch = rem / 26;
    const int* qp = &qs[ch*676 + cx];
    int oy0 = half*8;
    unsigned w0=0, w1=0, w2=0;
    #pragma unroll 1
    for (int r = oy0; r < oy0+11; r++) {
      int q = qp[r*26];
      unsigned inc = 1u << ((q & 7) << 2);
      int sel = q >> 3;
      w0 += (sel==0)?inc:0u; w1 += (sel==1)?inc:0u; w2 += (sel==2)?inc:0u;
    }
    unsigned base = (unsigned)(ch*442 + cx*17 + oy0);
    CH[base] = w0; CH[1326+base] = w1; CH[2652+base] = w2;
    #pragma unroll 1
    for (int i = 1; i < 8; i++) {
      int qr = qp[(oy0+i-1)*26];
      unsigned incr = 1u << ((qr & 7) << 2);
      int selr = qr >> 3;
      w0 -= (selr==0)?incr:0u; w1 -= (selr==1)?incr:0u; w2 -= (selr==2)?incr:0u;
      int qa = qp[(oy0+i+10)*26];
      unsigned inca = 1u << ((qa & 7) << 2);
      int sela = qa >> 3;
      w0 += (sela==0)?inca:0u; w1 += (sela==1)?inca:0u; w2 += (sela==2)?inca:0u;
      CH[base+i] = w0; CH[1326+base+i] = w1; CH[2652+base+i] = w2;
    }
  }
  __syncthreads();

  int oi = ty0 + ly, oj = tx0 + lx;
  if (oi >= 248 || oj >= 248) return;

  int mode[3];
  #pragma unroll
  for (int ch = 0; ch < 3; ch++) {
    unsigned a0=0,a1=0,a2=0,a3=0,a4=0;
    unsigned base = (unsigned)(ch*442 + lx*17 + ly);
    #pragma unroll
    for (int d = 0; d < 11; d++) {
      unsigned r0 = CH[base + d*17];
      unsigned r1 = CH[1326 + base + d*17];
      unsigned r2 = CH[2652 + base + d*17];
      a0 += r0 & 0x0F0F0F0Fu;
      a1 += (r0 >> 4) & 0x0F0F0F0Fu;
      a2 += r1 & 0x0F0F0F0Fu;
      a3 += (r1 >> 4) & 0x0F0F0F0Fu;
      a4 += r2;
    }
    // argmax via order-preserving key: equal counts -> larger (31-level) wins -> smallest level
    unsigned best = 0u;
    #define KEY(l, wreg) { unsigned cnt = ((wreg) >> ((((l)>>1)&3)*8)) & 255u; \
                           unsigned key = cnt*32u + (31u - (unsigned)(l)); \
                           best = (key > best) ? key : best; }
    KEY(0,a0) KEY(1,a1) KEY(2,a0) KEY(3,a1) KEY(4,a0) KEY(5,a1) KEY(6,a0) KEY(7,a1)
    KEY(8,a2) KEY(9,a3) KEY(10,a2) KEY(11,a3) KEY(12,a2) KEY(13,a3) KEY(14,a2) KEY(15,a3)
    { unsigned cnt = a4 & 255u; unsigned key = cnt*32u + 15u; best = (key > best) ? key : best; }
    #undef KEY
    mode[ch] = 31 - (int)(best & 31u);
  }
  int idx = (mode[0]*17 + mode[1])*17 + mode[2];
  const float* tp = T + (size_t)idx*32;
  size_t ob = ((size_t)(b*32)*248 + oi)*248 + oj;
  #pragma unroll
  for (int o2 = 0; o2 < 32; o2 += 4) {
    float4 v = *(const float4*)(tp + o2);
    dout[ob + (size_t)o2*61504]     = v.x;
    dout[ob + (size_t)(o2+1)*61504] = v.y;
    dout[ob + (size_t)(o2+2)*61504] = v.z;
    dout[ob + (size_t)(o2+3)*61504] = v.w;
  }
}

// ---------------- shared 3x3 conv, stride 3, pad 1 (248 -> 83), 4 outputs/thread ----------------
// v2: thread owns 4 consecutive-x outputs; the 12 needed columns per row come from 4
// aligned float4 loads (masked at edges) -> ~3x fewer load issues than 9-scalar/output.
__global__ void k_down(const float* __restrict__ in, float* __restrict__ out,
                       const float* __restrict__ scw, const float* __restrict__ scb) {
  const int Hin = 248, total = 128*83*21;
  int idx = blockIdx.x*256 + threadIdx.x;
  if (idx >= total) return;
  float w[9];
  #pragma unroll
  for (int i = 0; i < 9; i++) w[i] = rfl(scw[i]);
  float bias = rfl(scb[0]);
  int t = idx % 21; int r2 = idx / 21; int i = r2 % 83; int p = r2 / 83;
  const float* base = in + (size_t)p*Hin*Hin;
  float s0 = bias, s1 = bias, s2 = bias, s3 = bias;
  #pragma unroll
  for (int u = 0; u < 3; u++) {
    int r = 3*i - 1 + u;
    bool rok = ((unsigned)r < 248u);
    const float* rp = base + (size_t)r*Hin;
    float f[16];
    #pragma unroll
    for (int s4 = 0; s4 < 4; s4++) {
      int c0 = 12*t - 4 + 4*s4;
      float4 v = make_float4(0.f,0.f,0.f,0.f);
      if (rok && c0 >= 0 && c0 <= 244) v = *(const float4*)(rp + c0);
      f[s4*4+0] = v.x; f[s4*4+1] = v.y; f[s4*4+2] = v.z; f[s4*4+3] = v.w;
    }
    // f[k] = col 12t-4+k; output q needs cols 12t+3q-1+v -> f[3q+3+v]
    #pragma unroll
    for (int v = 0; v < 3; v++) {
      float wv = w[u*3+v];
      s0 += f[3+v]*wv;
      s1 += f[6+v]*wv;
      s2 += f[9+v]*wv;
      s3 += f[12+v]*wv;
    }
  }
  float* op = out + (size_t)p*6889 + (size_t)i*83 + 4*t;
  int j0 = 4*t;
  if (j0   < 83) op[0] = s0;
  if (j0+1 < 83) op[1] = s1;
  if (j0+2 < 83) op[2] = s2;
  if (j0+3 < 83) op[3] = s3;
}

// ---------------- merged tail downsamples: 83->28->10->4->2, one block per (b,c) ----------------
__global__ __launch_bounds__(256) void k_down_rest(const float* __restrict__ in, float* __restrict__ ws,
                                                   const float* __restrict__ scw, const float* __restrict__ scb) {
  __shared__ float buf[6889 + 784 + 100 + 16];   // 31.2 KB
  int tid = threadIdx.x; int p = blockIdx.x;     // 128 blocks
  float w[9];
  #pragma unroll
  for (int i = 0; i < 9; i++) w[i] = rfl(scw[i]);
  float bias = rfl(scb[0]);
  const float* src = in + (size_t)p*6889;
  for (int k = tid; k < 6889; k += 256) buf[k] = src[k];
  __syncthreads();
  const int HIN[4] = {83,28,10,4}, HOUT[4] = {28,10,4,2};
  const int OIN[4] = {0, 6889, 6889+784, 6889+784+100};
  const size_t GOFF[4] = {P_D2, P_D3, P_D4, P_D5};
  #pragma unroll
  for (int st = 0; st < 4; st++) {
    const int hin = HIN[st], hout = HOUT[st];
    const float* bi = buf + OIN[st];
    float* bo = buf + OIN[st] + hin*hin;
    float* go = ws + GOFF[st] + (size_t)p*(hout*hout);
    for (int k = tid; k < hout*hout; k += 256) {
      int i = k/hout, j = k - i*hout;
      float s = bias;
      #pragma unroll
      for (int u = 0; u < 3; u++) {
        int r = 3*i - 1 + u;
        if ((unsigned)r < (unsigned)hin) {
          #pragma unroll
          for (int v = 0; v < 3; v++) {
            int cc = 3*j - 1 + v;
            if ((unsigned)cc < (unsigned)hin) s += bi[r*hin + cc]*w[u*3+v];
          }
        }
      }
      bo[k] = s; go[k] = s;
    }
    __syncthreads();
  }
}

// ---------------- pyramid: pk-FMA core + FULLY UNROLLED level loop ----------------
// The 40 phase-C zt addresses are level-invariant and n/inv/off fold to literals when
// unrolled -> hoists ~level-repeated addressing out of the hot path. VGPR budget: 36 now,
// headroom to 64 before the 8-block LDS occupancy cap.
#define NSP_PACK (83u | (28u<<7) | (10u<<14) | (4u<<21) | (2u<<28))
#define ZROT(r) ((((r)&3) ^ (((r)>>2)&3)) << 3)
__global__ __launch_bounds__(256) void k_accum(const float* __restrict__ ws,
                                               const float* __restrict__ iaw,
                                               const float* __restrict__ ibw,
                                               float* __restrict__ score) {
  __shared__ __align__(16) float hrow[14*96];   // 5.25 KB
  __shared__ __align__(16) float zt[36*96];     // 13.8 KB
  int tid = threadIdx.x;
  int c = blockIdx.y, b = blockIdx.z;
  int tx0 = (blockIdx.x & 3)*64, ty0 = (blockIdx.x >> 2)*32;
  int half = tid >> 7;                         // 0 = branch A, 1 = branch B
  int t2 = tid & 127;
  int lx4 = (t2 & 15)*4, lyt = t2 >> 4;        // 16x8 threads, 4w x 4h px each

  const float* wp = half ? ibw : iaw;
  float w[25];
  #pragma unroll
  for (int i = 0; i < 25; i++) w[i] = rfl(wp[i]);
  float s_ = rfl(ws[1184 + half*64 + c]);
  float C_ = rfl(ws[1216 + half*64 + c]);

  int bzy = tid >> 3;          // 0..31
  int bzx0 = tid & 7;

  float acc[16];
  #pragma unroll
  for (int i = 0; i < 16; i++) acc[i] = 0.f;

  size_t off = P_D1;
  #pragma unroll
  for (int lvl = 0; lvl < 5; lvl++) {
    const int n = (int)((NSP_PACK >> (7*lvl)) & 127u);
    const float inv = (float)n * (1.f/256.f);
    float f0 = ((float)(ty0-2)+0.5f)*inv - 0.5f;
    float f1 = ((float)(ty0+33)+0.5f)*inv - 0.5f;
    int yb0 = min(max((int)floorf(f0),0), n-2);
    int yb1 = min(max((int)floorf(f1),0), n-2);
    int rows = yb1 - yb0 + 2;
    const float* dp = ws + off + (size_t)(b*32+c)*(n*n);

    // ---- A: stage x-lerped rows ----
    #pragma unroll 1
    for (int k = tid; k < rows*68; k += 256) {
      int r = k/68, zx = k - r*68;
      int gx = tx0 + zx - 2;
      float h = 0.f;
      if ((unsigned)gx < 256u) {
        float f = ((float)gx + 0.5f)*inv - 0.5f;
        float ff = floorf(f);
        int i0 = (int)ff;
        int xb = min(max(i0,0), n-2);
        float wx = (i0 < 0) ? 0.f : (i0 > n-2 ? 1.f : f - ff);
        const float* rp = dp + (yb0 + r)*n + xb;
        h = rp[0] + wx*(rp[1] - rp[0]);
      }
      hrow[r*96 + ((r&3)<<3) + zx] = h;
    }
    __syncthreads();

    // ---- B: build unique z tile (y-lerp) ----
    {
      int gy = ty0 - 2 + bzy;
      float f = ((float)gy + 0.5f)*inv - 0.5f;
      float ff = floorf(f);
      int i0 = (int)ff;
      int yb = min(max(i0,0), n-2);
      float wy = (i0 < 0) ? 0.f : (i0 > n-2 ? 1.f : f - ff);
      bool vy = ((unsigned)gy < 256u);
      int rel = yb - yb0;
      int ra = rel*96 + ((rel&3)<<3);
      int rb = (rel+1)*96 + (((rel+1)&3)<<3);
      int zr0 = bzy*96 + ZROT(bzy);
      #pragma unroll
      for (int s = 0; s < 9; s++) {
        int zx = bzx0 + s*8;
        if (zx < 68) {
          float v = 0.f;
          if (vy) { float a = hrow[ra + zx], bb = hrow[rb + zx]; v = a + wy*(bb - a); }
          zt[zr0 + zx] = v;
        }
      }
      #pragma unroll 1
      for (int k = tid; k < 4*68; k += 256) {
        int zy = 32 + k/68; int zx = k - (k/68)*68;
        int gy2 = ty0 - 2 + zy;
        float v = 0.f;
        if ((unsigned)gy2 < 256u) {
          float f2 = ((float)gy2 + 0.5f)*inv - 0.5f;
          float ff2 = floorf(f2);
          int i02 = (int)ff2;
          int yb2 = min(max(i02,0), n-2);
          float wy2 = (i02 < 0) ? 0.f : (i02 > n-2 ? 1.f : f2 - ff2);
          int rel2 = yb2 - yb0;
          float a = hrow[rel2*96 + ((rel2&3)<<3) + zx];
          float bb = hrow[(rel2+1)*96 + (((rel2+1)&3)<<3) + zx];
          v = a + wy2*(bb - a);
        }
        zt[zy*96 + ZROT(zy) + zx] = v;
      }
    }
    __syncthreads();

    // ---- C: conv, branch-split, float2 column-pairs (pk-FMA) ----
    f32x2 cc2[4][2];
    #pragma unroll
    for (int p = 0; p < 4; p++)
      #pragma unroll
      for (int j2 = 0; j2 < 2; j2++) cc2[p][j2] = (f32x2)(0.f);
    #pragma unroll
    for (int zr = 0; zr < 8; zr++) {
      int row = 4*lyt + zr;
      int o = row*96 + ZROT(row) + lx4;
      float4 a0 = *(const float4*)&zt[o];
      float4 a1 = *(const float4*)&zt[o+4];
      float zz[8] = {a0.x,a0.y,a0.z,a0.w,a1.x,a1.y,a1.z,a1.w};
      #pragma unroll
      for (int p = 0; p < 4; p++) {
        int r = zr - p;
        if (r >= 0 && r < 5) {
          #pragma unroll
          for (int v = 0; v < 5; v++) {
            float wv = w[r*5+v];
            cc2[p][0] += (f32x2){zz[v],   zz[v+1]} * wv;
            cc2[p][1] += (f32x2){zz[v+2], zz[v+3]} * wv;
          }
        }
      }
    }
    #pragma unroll
    for (int p = 0; p < 4; p++)
      #pragma unroll
      for (int j2 = 0; j2 < 2; j2++) {
        f32x2 v2 = cc2[p][j2]*s_ + C_;
        #pragma unroll
        for (int e = 0; e < 2; e++) {
          float v = v2[e];
          acc[p*4 + j2*2 + e] += (v >= 0.f) ? v : 0.01f*v;
        }
      }
    off += (size_t)128*n*n;
  }
  int oy = ty0 + 4*lyt, ox = tx0 + lx4;
  size_t base = ((size_t)(b*64 + half*32 + c)*256 + oy)*256 + ox;
  #pragma unroll
  for (int p = 0; p < 4; p++)
    *(float4*)&score[base + (size_t)p*256] = make_float4(acc[p*4],acc[p*4+1],acc[p*4+2],acc[p*4+3]);
}

// ---------------- ft pass v6 + XCD-grouped block mapping (round-14 measured best) ----------------
__global__ __launch_bounds__(256) void k_ft(const float* __restrict__ in,
                                            float* __restrict__ out,
                                            const float* __restrict__ P, float scale) {
  __shared__ __align__(8) float Bf2[8*271*2];  // [(r>>1)*271 + 5+col]*2 + (r&1); 17.3 KB
  int tid = threadIdx.x;         // = column
  int d = blockIdx.x;            // 0..4095
  int qlo = d & 7, rest = d >> 3;
  int xt = rest & 15, qhi = rest >> 4;
  int q = qlo + 8*qhi;           // 0..255 = c + 64*b
  int c = q & 63, b = q >> 6;
  int ty0 = xt * 16;
  float fs1 = rfl(P[1312+c]), fc1 = rfl(P[1376+c]), fs2 = rfl(P[1440+c]), fc2 = rfl(P[1504+c]);
  const float* ip = in + (size_t)(b*64 + c)*65536 + tid;

  // halo zeros: 8 row-pairs x 10 halo cols (idx 0..4 = cols -5..-1, 261..265 = cols 256..260)
  if (tid < 80) {
    int r2 = tid / 10, qq = tid - r2*10;
    int pc = (qq < 5 ? qq : 256 + qq);
    *(f32x2*)&Bf2[(r2*271 + pc)*2] = (f32x2)(0.f);
  }

  float yreg[16];
  float win[11];
  float run = 0.f, prev = 0.f;
  #pragma unroll
  for (int s = 0; s < 26; s++) {
    int gy = ty0 + s - 5;
    float yv = 0.f;
    if ((unsigned)gy < 256u) {
      float t = ip[(size_t)gy*256]*fs1 + fc1;
      t = (t > 0.1f) ? t : 0.7f*t;
      yv = t*fs2 + fc2;
    }
    win[s % 11] = yv;
    run += yv;
    if (s >= 5 && s <= 20) yreg[s-5] = yv;
    if (s >= 10) {
      int r = s - 10;                         // 0..15
      if ((r & 1) == 0) prev = run;
      else *(f32x2*)&Bf2[((r>>1)*271 + 5 + tid)*2] = (f32x2){prev, run};
      run -= win[r % 11];
    }
  }
  __syncthreads();

  const size_t ob = (size_t)(b*64 + c)*65536 + (size_t)ty0*256 + tid;
  #pragma unroll
  for (int r2 = 0; r2 < 8; r2++) {
    const float* bp = &Bf2[(r2*271 + tid)*2];  // window cols tid-5..tid+5 -> pair idx tid..tid+10
    f32x2 s2 = *(const f32x2*)bp;
    #pragma unroll
    for (int dd = 1; dd < 11; dd++) s2 += *(const f32x2*)(bp + 2*dd);
    float y0 = yreg[r2*2], y1 = yreg[r2*2+1];
    float sig0 = 1.f/(1.f + __expf(-(y0 - s2.x*(1.f/121.f))));
    float sig1 = 1.f/(1.f + __expf(-(y1 - s2.y*(1.f/121.f))));
    out[ob + (size_t)(r2*2)*256]   = y0*sig0*scale;
    out[ob + (size_t)(r2*2+1)*256] = y1*sig1*scale;
  }
}

// ---------------- launch ----------------
extern "C" void kernel_launch(void* const* d_in, const int* in_sizes, int n_in,
                              void* d_out, int out_size, void* d_ws, size_t ws_size,
                              hipStream_t stream) {
  const float* x = (const float*)d_in[0];
  float* ws = (float*)d_ws;
  float* out = (float*)d_out;

  PrepArgs pa;
  for (int i = 0; i < 39; i++) pa.p[i] = (const float*)d_in[i];
  k_table<<<dim3(20), dim3(256), 0, stream>>>(pa, ws, ws + P_TAB);

  k_mode_mlp<<<dim3(16,16,4), dim3(16,16), 0, stream>>>(x, ws + P_TAB, ws + P_D);

  const float* scw = (const float*)d_in[17];
  const float* scb = (const float*)d_in[18];
  {
    int total = 128*83*21;   // 4 outputs per thread
    k_down<<<dim3((total+255)/256), dim3(256), 0, stream>>>(ws + P_D, ws + P_D1, scw, scb);
  }
  k_down_rest<<<dim3(128), dim3(256), 0, stream>>>(ws + P_D1, ws, scw, scb);

  k_accum<<<dim3(32,32,4), dim3(256), 0, stream>>>(ws, (const float*)d_in[19],
                                                   (const float*)d_in[25], ws + P_SCORE);

  // ft x3 (v6 + XCD-grouped mapping), ping-pong; /5 folded into last pass
  k_ft<<<dim3(4096), dim3(256), 0, stream>>>(ws + P_SCORE, out, ws, 1.f);
  k_ft<<<dim3(4096), dim3(256), 0, stream>>>(out, ws + P_SCORE, ws, 1.f);
  k_ft<<<dim3(4096), dim3(256), 0, stream>>>(ws + P_SCORE, out, ws, 0.2f);
}

// Round 16
// 339.636 us; speedup vs baseline: 1.4082x; 1.4082x over previous
//
#include <hip/hip_runtime.h>
#include <math.h>

#define EPSI 1e-5f

typedef float f32x2 __attribute__((ext_vector_type(2)));

// ---------------- workspace layout (floats) ----------------
#define P_D1 2048                    // 128*83*83 = 881792
#define P_D2 (P_D1 + 128*83*83)
#define P_D3 (P_D2 + 128*28*28)
#define P_D4 (P_D3 + 128*10*10)
#define P_D5 (P_D4 + 128*4*4)
#define P_SCORE (P_D5 + 128*2*2)     // 4*64*256*256 = 16777216 floats
#define P_D  P_SCORE                 // d (4,32,248,248) = 7.87M floats, aliases score head
#define P_TAB (P_SCORE + 8388608)    // 17^3 x 32 MLP table in dead tail of score region

__device__ __forceinline__ float rfl(float x) {
  return __builtin_bit_cast(float, __builtin_amdgcn_readfirstlane(__builtin_bit_cast(int, x)));
}

struct PrepArgs { const float* p[39]; };

// ---------------- prep (in-LDS, per block) + 17^3 -> 32 MLP lookup table ----------------
__global__ __launch_bounds__(256) void k_table(PrepArgs a, float* __restrict__ P,
                                               float* __restrict__ T) {
  __shared__ float Pl[1568];
  int t = threadIdx.x;
  {
    const float *w1=a.p[1],*b1=a.p[2],*w2=a.p[3],*b2=a.p[4],*g1=a.p[5],*bb1=a.p[6],*m1=a.p[7],*v1=a.p[8];
    const float *w3=a.p[9],*b3=a.p[10],*w4=a.p[11],*b4=a.p[12],*g2=a.p[13],*bb2=a.p[14],*m2=a.p[15],*v2=a.p[16];
    for (int i=t;i<96;i+=256){ int o=i/3; float s=g1[o]/sqrtf(v1[o]+EPSI); Pl[i]=w1[i]*w2[o]*s; }
    for (int o=t;o<32;o+=256){ float s=g1[o]/sqrtf(v1[o]+EPSI); Pl[96+o]=(b1[o]*w2[o]+b2[o]-m1[o])*s+bb1[o]; }
    for (int i=t;i<1024;i+=256){ int o2=i/32; float s=g2[o2]/sqrtf(v2[o2]+EPSI); Pl[128+i]=w3[i]*w4[o2]*s; }
    for (int o=t;o<32;o+=256){ float s=g2[o]/sqrtf(v2[o]+EPSI); Pl[1152+o]=(b3[o]*w4[o]+b4[o]-m2[o])*s+bb2[o]; }
    const float *iag=a.p[21],*iab=a.p[22],*iam=a.p[23],*iav=a.p[24],*iabias=a.p[20];
    for (int c=t;c<32;c+=256){ float s=iag[c]/sqrtf(iav[c]+EPSI); Pl[1184+c]=s; Pl[1216+c]=(iabias[0]-iam[c])*s+iab[c]; }
    const float *ibg=a.p[27],*ibb=a.p[28],*ibm=a.p[29],*ibv=a.p[30],*ibbias=a.p[26];
    for (int c=t;c<32;c+=256){ float s=ibg[c]/sqrtf(ibv[c]+EPSI); Pl[1248+c]=s; Pl[1280+c]=(ibbias[0]-ibm[c])*s+ibb[c]; }
    const float *f1g=a.p[31],*f1b=a.p[32],*f1m=a.p[33],*f1v=a.p[34];
    for (int c=t;c<64;c+=256){ float s=f1g[c]/sqrtf(f1v[c]+EPSI); Pl[1312+c]=s; Pl[1376+c]=f1b[c]-f1m[c]*s; }
    const float *f2g=a.p[35],*f2b=a.p[36],*f2m=a.p[37],*f2v=a.p[38];
    for (int c=t;c<64;c+=256){ float s=f2g[c]/sqrtf(f2v[c]+EPSI); Pl[1440+c]=s; Pl[1504+c]=f2b[c]-f2m[c]*s; }
  }
  __syncthreads();
  if (blockIdx.x == 0) {
    for (int i = t; i < 1568; i += 256) P[i] = Pl[i];
  }
  int idx = blockIdx.x*256 + t;
  if (idx >= 4913) return;
  int m0 = idx/289; int rem = idx - m0*289; int m1 = rem/17; int m2 = rem - m1*17;
  float md0 = (float)m0*0.0625f, md1 = (float)m1*0.0625f, md2 = (float)m2*0.0625f;
  const float* A1 = Pl;           const float* C1 = Pl + 96;
  const float* A2 = Pl + 128;     const float* C2 = Pl + 1152;
  float h[32];
  #pragma unroll
  for (int o = 0; o < 32; o++) {
    float v = C1[o] + A1[o*3]*md0 + A1[o*3+1]*md1 + A1[o*3+2]*md2;
    h[o] = (v >= 0.f) ? v : 0.01f*v;
  }
  float* tp = T + (size_t)idx*32;
  #pragma unroll
  for (int o2 = 0; o2 < 32; o2++) {
    float acc = C2[o2];
    #pragma unroll
    for (int o = 0; o < 32; o++) acc += A2[o2*32+o]*h[o];
    tp[o2] = (acc >= 0.f) ? acc : 0.01f*acc;
  }
}

// ---------------- quantize + mode-pool(11,1,1) via separable column-histograms + table ----------
__global__ __launch_bounds__(256) void k_mode_mlp(const float* __restrict__ x,
                                                 const float* __restrict__ T,
                                                 float* __restrict__ dout) {
  __shared__ int qs[3*676];          // 8.1 KB
  __shared__ unsigned CH[3*1326];    // 15.9 KB; plane w: w*1326 + ch*442 + cx*17 + oy
  int lx = threadIdx.x, ly = threadIdx.y;
  int tid = ly*16 + lx;
  int tx0 = blockIdx.x*16, ty0 = blockIdx.y*16;
  int b = blockIdx.z;
  for (int k = tid; k < 3*676; k += 256) {
    int cch = k/676; int rem = k - cch*676; int r = rem/26; int cc = rem - r*26;
    int gy = ty0 + r - 1, gx = tx0 + cc - 1;
    int q = 0;
    if ((unsigned)gy < 256u && (unsigned)gx < 256u) {
      float v = x[((size_t)(b*3+cch)*256 + gy)*256 + gx];
      q = (int)rintf(v*255.0f/16.0f);
      q = q < 0 ? 0 : (q > 16 ? 16 : q);
    }
    qs[k] = q;
  }
  __syncthreads();

  if (tid < 156) {
    int half = tid & 1; int rem = tid >> 1;
    int cx = rem % 26; int ch = rem / 26;
    const int* qp = &qs[ch*676 + cx];
    int oy0 = half*8;
    unsigned w0=0, w1=0, w2=0;
    #pragma unroll 1
    for (int r = oy0; r < oy0+11; r++) {
      int q = qp[r*26];
      unsigned inc = 1u << ((q & 7) << 2);
      int sel = q >> 3;
      w0 += (sel==0)?inc:0u; w1 += (sel==1)?inc:0u; w2 += (sel==2)?inc:0u;
    }
    unsigned base = (unsigned)(ch*442 + cx*17 + oy0);
    CH[base] = w0; CH[1326+base] = w1; CH[2652+base] = w2;
    #pragma unroll 1
    for (int i = 1; i < 8; i++) {
      int qr = qp[(oy0+i-1)*26];
      unsigned incr = 1u << ((qr & 7) << 2);
      int selr = qr >> 3;
      w0 -= (selr==0)?incr:0u; w1 -= (selr==1)?incr:0u; w2 -= (selr==2)?incr:0u;
      int qa = qp[(oy0+i+10)*26];
      unsigned inca = 1u << ((qa & 7) << 2);
      int sela = qa >> 3;
      w0 += (sela==0)?inca:0u; w1 += (sela==1)?inca:0u; w2 += (sela==2)?inca:0u;
      CH[base+i] = w0; CH[1326+base+i] = w1; CH[2652+base+i] = w2;
    }
  }
  __syncthreads();

  int oi = ty0 + ly, oj = tx0 + lx;
  if (oi >= 248 || oj >= 248) return;

  int mode[3];
  #pragma unroll
  for (int ch = 0; ch < 3; ch++) {
    unsigned a0=0,a1=0,a2=0,a3=0,a4=0;
    unsigned base = (unsigned)(ch*442 + lx*17 + ly);
    #pragma unroll
    for (int d = 0; d < 11; d++) {
      unsigned r0 = CH[base + d*17];
      unsigned r1 = CH[1326 + base + d*17];
      unsigned r2 = CH[2652 + base + d*17];
      a0 += r0 & 0x0F0F0F0Fu;
      a1 += (r0 >> 4) & 0x0F0F0F0Fu;
      a2 += r1 & 0x0F0F0F0Fu;
      a3 += (r1 >> 4) & 0x0F0F0F0Fu;
      a4 += r2;
    }
    // argmax via order-preserving key: equal counts -> larger (31-level) wins -> smallest level
    unsigned best = 0u;
    #define KEY(l, wreg) { unsigned cnt = ((wreg) >> ((((l)>>1)&3)*8)) & 255u; \
                           unsigned key = cnt*32u + (31u - (unsigned)(l)); \
                           best = (key > best) ? key : best; }
    KEY(0,a0) KEY(1,a1) KEY(2,a0) KEY(3,a1) KEY(4,a0) KEY(5,a1) KEY(6,a0) KEY(7,a1)
    KEY(8,a2) KEY(9,a3) KEY(10,a2) KEY(11,a3) KEY(12,a2) KEY(13,a3) KEY(14,a2) KEY(15,a3)
    { unsigned cnt = a4 & 255u; unsigned key = cnt*32u + 15u; best = (key > best) ? key : best; }
    #undef KEY
    mode[ch] = 31 - (int)(best & 31u);
  }
  int idx = (mode[0]*17 + mode[1])*17 + mode[2];
  const float* tp = T + (size_t)idx*32;
  size_t ob = ((size_t)(b*32)*248 + oi)*248 + oj;
  #pragma unroll
  for (int o2 = 0; o2 < 32; o2 += 4) {
    float4 v = *(const float4*)(tp + o2);
    dout[ob + (size_t)o2*61504]     = v.x;
    dout[ob + (size_t)(o2+1)*61504] = v.y;
    dout[ob + (size_t)(o2+2)*61504] = v.z;
    dout[ob + (size_t)(o2+3)*61504] = v.w;
  }
}

// ---------------- shared 3x3 conv, stride 3, pad 1 (248 -> 83), 4 outputs/thread ----------------
__global__ void k_down(const float* __restrict__ in, float* __restrict__ out,
                       const float* __restrict__ scw, const float* __restrict__ scb) {
  const int Hin = 248, total = 128*83*21;
  int idx = blockIdx.x*256 + threadIdx.x;
  if (idx >= total) return;
  float w[9];
  #pragma unroll
  for (int i = 0; i < 9; i++) w[i] = rfl(scw[i]);
  float bias = rfl(scb[0]);
  int t = idx % 21; int r2 = idx / 21; int i = r2 % 83; int p = r2 / 83;
  const float* base = in + (size_t)p*Hin*Hin;
  float s0 = bias, s1 = bias, s2 = bias, s3 = bias;
  #pragma unroll
  for (int u = 0; u < 3; u++) {
    int r = 3*i - 1 + u;
    bool rok = ((unsigned)r < 248u);
    const float* rp = base + (size_t)r*Hin;
    float f[16];
    #pragma unroll
    for (int s4 = 0; s4 < 4; s4++) {
      int c0 = 12*t - 4 + 4*s4;
      float4 v = make_float4(0.f,0.f,0.f,0.f);
      if (rok && c0 >= 0 && c0 <= 244) v = *(const float4*)(rp + c0);
      f[s4*4+0] = v.x; f[s4*4+1] = v.y; f[s4*4+2] = v.z; f[s4*4+3] = v.w;
    }
    #pragma unroll
    for (int v = 0; v < 3; v++) {
      float wv = w[u*3+v];
      s0 += f[3+v]*wv;
      s1 += f[6+v]*wv;
      s2 += f[9+v]*wv;
      s3 += f[12+v]*wv;
    }
  }
  float* op = out + (size_t)p*6889 + (size_t)i*83 + 4*t;
  int j0 = 4*t;
  if (j0   < 83) op[0] = s0;
  if (j0+1 < 83) op[1] = s1;
  if (j0+2 < 83) op[2] = s2;
  if (j0+3 < 83) op[3] = s3;
}

// ---------------- merged tail downsamples: 83->28->10->4->2, one block per (b,c) ----------------
__global__ __launch_bounds__(256) void k_down_rest(const float* __restrict__ in, float* __restrict__ ws,
                                                   const float* __restrict__ scw, const float* __restrict__ scb) {
  __shared__ float buf[6889 + 784 + 100 + 16];   // 31.2 KB
  int tid = threadIdx.x; int p = blockIdx.x;     // 128 blocks
  float w[9];
  #pragma unroll
  for (int i = 0; i < 9; i++) w[i] = rfl(scw[i]);
  float bias = rfl(scb[0]);
  const float* src = in + (size_t)p*6889;
  for (int k = tid; k < 6889; k += 256) buf[k] = src[k];
  __syncthreads();
  const int HIN[4] = {83,28,10,4}, HOUT[4] = {28,10,4,2};
  const int OIN[4] = {0, 6889, 6889+784, 6889+784+100};
  const size_t GOFF[4] = {P_D2, P_D3, P_D4, P_D5};
  #pragma unroll
  for (int st = 0; st < 4; st++) {
    const int hin = HIN[st], hout = HOUT[st];
    const float* bi = buf + OIN[st];
    float* bo = buf + OIN[st] + hin*hin;
    float* go = ws + GOFF[st] + (size_t)p*(hout*hout);
    for (int k = tid; k < hout*hout; k += 256) {
      int i = k/hout, j = k - i*hout;
      float s = bias;
      #pragma unroll
      for (int u = 0; u < 3; u++) {
        int r = 3*i - 1 + u;
        if ((unsigned)r < (unsigned)hin) {
          #pragma unroll
          for (int v = 0; v < 3; v++) {
            int cc = 3*j - 1 + v;
            if ((unsigned)cc < (unsigned)hin) s += bi[r*hin + cc]*w[u*3+v];
          }
        }
      }
      bo[k] = s; go[k] = s;
    }
    __syncthreads();
  }
}

// ---------------- pyramid: round-14 form (82.7 us measured; level loop NOT unrolled) ----------
// Round-15 lesson: full unroll -> 5 levels' staging state live at once -> VGPR 192,
// occupancy 11%, 220 us. Occupancy law via registers. Keep #pragma unroll 1.
#define NSP_PACK (83u | (28u<<7) | (10u<<14) | (4u<<21) | (2u<<28))
#define ZROT(r) ((((r)&3) ^ (((r)>>2)&3)) << 3)
__global__ __launch_bounds__(256) void k_accum(const float* __restrict__ ws,
                                               const float* __restrict__ iaw,
                                               const float* __restrict__ ibw,
                                               float* __restrict__ score) {
  __shared__ __align__(16) float hrow[14*96];   // 5.25 KB
  __shared__ __align__(16) float zt[36*96];     // 13.8 KB
  int tid = threadIdx.x;
  int c = blockIdx.y, b = blockIdx.z;
  int tx0 = (blockIdx.x & 3)*64, ty0 = (blockIdx.x >> 2)*32;
  int half = tid >> 7;                         // 0 = branch A, 1 = branch B
  int t2 = tid & 127;
  int lx4 = (t2 & 15)*4, lyt = t2 >> 4;        // 16x8 threads, 4w x 4h px each

  const float* wp = half ? ibw : iaw;
  float w[25];
  #pragma unroll
  for (int i = 0; i < 25; i++) w[i] = rfl(wp[i]);
  float s_ = rfl(ws[1184 + half*64 + c]);
  float C_ = rfl(ws[1216 + half*64 + c]);

  int bzy = tid >> 3;          // 0..31
  int bzx0 = tid & 7;

  float acc[16];
  #pragma unroll
  for (int i = 0; i < 16; i++) acc[i] = 0.f;

  size_t off = P_D1;
  #pragma unroll 1
  for (int lvl = 0; lvl < 5; lvl++) {
    const int n = (int)((NSP_PACK >> (7*lvl)) & 127u);
    const float inv = (float)n * (1.f/256.f);
    float f0 = ((float)(ty0-2)+0.5f)*inv - 0.5f;
    float f1 = ((float)(ty0+33)+0.5f)*inv - 0.5f;
    int yb0 = min(max((int)floorf(f0),0), n-2);
    int yb1 = min(max((int)floorf(f1),0), n-2);
    int rows = yb1 - yb0 + 2;
    const float* dp = ws + off + (size_t)(b*32+c)*(n*n);

    // ---- A: stage x-lerped rows ----
    #pragma unroll 1
    for (int k = tid; k < rows*68; k += 256) {
      int r = k/68, zx = k - r*68;
      int gx = tx0 + zx - 2;
      float h = 0.f;
      if ((unsigned)gx < 256u) {
        float f = ((float)gx + 0.5f)*inv - 0.5f;
        float ff = floorf(f);
        int i0 = (int)ff;
        int xb = min(max(i0,0), n-2);
        float wx = (i0 < 0) ? 0.f : (i0 > n-2 ? 1.f : f - ff);
        const float* rp = dp + (yb0 + r)*n + xb;
        h = rp[0] + wx*(rp[1] - rp[0]);
      }
      hrow[r*96 + ((r&3)<<3) + zx] = h;
    }
    __syncthreads();

    // ---- B: build unique z tile (y-lerp) ----
    {
      int gy = ty0 - 2 + bzy;
      float f = ((float)gy + 0.5f)*inv - 0.5f;
      float ff = floorf(f);
      int i0 = (int)ff;
      int yb = min(max(i0,0), n-2);
      float wy = (i0 < 0) ? 0.f : (i0 > n-2 ? 1.f : f - ff);
      bool vy = ((unsigned)gy < 256u);
      int rel = yb - yb0;
      int ra = rel*96 + ((rel&3)<<3);
      int rb = (rel+1)*96 + (((rel+1)&3)<<3);
      int zr0 = bzy*96 + ZROT(bzy);
      #pragma unroll
      for (int s = 0; s < 9; s++) {
        int zx = bzx0 + s*8;
        if (zx < 68) {
          float v = 0.f;
          if (vy) { float a = hrow[ra + zx], bb = hrow[rb + zx]; v = a + wy*(bb - a); }
          zt[zr0 + zx] = v;
        }
      }
      #pragma unroll 1
      for (int k = tid; k < 4*68; k += 256) {
        int zy = 32 + k/68; int zx = k - (k/68)*68;
        int gy2 = ty0 - 2 + zy;
        float v = 0.f;
        if ((unsigned)gy2 < 256u) {
          float f2 = ((float)gy2 + 0.5f)*inv - 0.5f;
          float ff2 = floorf(f2);
          int i02 = (int)ff2;
          int yb2 = min(max(i02,0), n-2);
          float wy2 = (i02 < 0) ? 0.f : (i02 > n-2 ? 1.f : f2 - ff2);
          int rel2 = yb2 - yb0;
          float a = hrow[rel2*96 + ((rel2&3)<<3) + zx];
          float bb = hrow[(rel2+1)*96 + (((rel2+1)&3)<<3) + zx];
          v = a + wy2*(bb - a);
        }
        zt[zy*96 + ZROT(zy) + zx] = v;
      }
    }
    __syncthreads();

    // ---- C: conv, branch-split, float2 column-pairs (pk-FMA) ----
    f32x2 cc2[4][2];
    #pragma unroll
    for (int p = 0; p < 4; p++)
      #pragma unroll
      for (int j2 = 0; j2 < 2; j2++) cc2[p][j2] = (f32x2)(0.f);
    #pragma unroll
    for (int zr = 0; zr < 8; zr++) {
      int row = 4*lyt + zr;
      int o = row*96 + ZROT(row) + lx4;
      float4 a0 = *(const float4*)&zt[o];
      float4 a1 = *(const float4*)&zt[o+4];
      float zz[8] = {a0.x,a0.y,a0.z,a0.w,a1.x,a1.y,a1.z,a1.w};
      #pragma unroll
      for (int p = 0; p < 4; p++) {
        int r = zr - p;
        if (r >= 0 && r < 5) {
          #pragma unroll
          for (int v = 0; v < 5; v++) {
            float wv = w[r*5+v];
            cc2[p][0] += (f32x2){zz[v],   zz[v+1]} * wv;
            cc2[p][1] += (f32x2){zz[v+2], zz[v+3]} * wv;
          }
        }
      }
    }
    #pragma unroll
    for (int p = 0; p < 4; p++)
      #pragma unroll
      for (int j2 = 0; j2 < 2; j2++) {
        f32x2 v2 = cc2[p][j2]*s_ + C_;
        #pragma unroll
        for (int e = 0; e < 2; e++) {
          float v = v2[e];
          acc[p*4 + j2*2 + e] += (v >= 0.f) ? v : 0.01f*v;
        }
      }
    off += (size_t)128*n*n;
  }
  int oy = ty0 + 4*lyt, ox = tx0 + lx4;
  size_t base = ((size_t)(b*64 + half*32 + c)*256 + oy)*256 + ox;
  #pragma unroll
  for (int p = 0; p < 4; p++)
    *(float4*)&score[base + (size_t)p*256] = make_float4(acc[p*4],acc[p*4+1],acc[p*4+2],acc[p*4+3]);
}

// ---------------- ft pass v6 + XCD-grouped block mapping (round-14 measured best) ----------------
__global__ __launch_bounds__(256) void k_ft(const float* __restrict__ in,
                                            float* __restrict__ out,
                                            const float* __restrict__ P, float scale) {
  __shared__ __align__(8) float Bf2[8*271*2];  // [(r>>1)*271 + 5+col]*2 + (r&1); 17.3 KB
  int tid = threadIdx.x;         // = column
  int d = blockIdx.x;            // 0..4095
  int qlo = d & 7, rest = d >> 3;
  int xt = rest & 15, qhi = rest >> 4;
  int q = qlo + 8*qhi;           // 0..255 = c + 64*b
  int c = q & 63, b = q >> 6;
  int ty0 = xt * 16;
  float fs1 = rfl(P[1312+c]), fc1 = rfl(P[1376+c]), fs2 = rfl(P[1440+c]), fc2 = rfl(P[1504+c]);
  const float* ip = in + (size_t)(b*64 + c)*65536 + tid;

  // halo zeros: 8 row-pairs x 10 halo cols (idx 0..4 = cols -5..-1, 261..265 = cols 256..260)
  if (tid < 80) {
    int r2 = tid / 10, qq = tid - r2*10;
    int pc = (qq < 5 ? qq : 256 + qq);
    *(f32x2*)&Bf2[(r2*271 + pc)*2] = (f32x2)(0.f);
  }

  float yreg[16];
  float win[11];
  float run = 0.f, prev = 0.f;
  #pragma unroll
  for (int s = 0; s < 26; s++) {
    int gy = ty0 + s - 5;
    float yv = 0.f;
    if ((unsigned)gy < 256u) {
      float t = ip[(size_t)gy*256]*fs1 + fc1;
      t = (t > 0.1f) ? t : 0.7f*t;
      yv = t*fs2 + fc2;
    }
    win[s % 11] = yv;
    run += yv;
    if (s >= 5 && s <= 20) yreg[s-5] = yv;
    if (s >= 10) {
      int r = s - 10;                         // 0..15
      if ((r & 1) == 0) prev = run;
      else *(f32x2*)&Bf2[((r>>1)*271 + 5 + tid)*2] = (f32x2){prev, run};
      run -= win[r % 11];
    }
  }
  __syncthreads();

  const size_t ob = (size_t)(b*64 + c)*65536 + (size_t)ty0*256 + tid;
  #pragma unroll
  for (int r2 = 0; r2 < 8; r2++) {
    const float* bp = &Bf2[(r2*271 + tid)*2];  // window cols tid-5..tid+5 -> pair idx tid..tid+10
    f32x2 s2 = *(const f32x2*)bp;
    #pragma unroll
    for (int dd = 1; dd < 11; dd++) s2 += *(const f32x2*)(bp + 2*dd);
    float y0 = yreg[r2*2], y1 = yreg[r2*2+1];
    float sig0 = 1.f/(1.f + __expf(-(y0 - s2.x*(1.f/121.f))));
    float sig1 = 1.f/(1.f + __expf(-(y1 - s2.y*(1.f/121.f))));
    out[ob + (size_t)(r2*2)*256]   = y0*sig0*scale;
    out[ob + (size_t)(r2*2+1)*256] = y1*sig1*scale;
  }
}

// ---------------- launch ----------------
extern "C" void kernel_launch(void* const* d_in, const int* in_sizes, int n_in,
                              void* d_out, int out_size, void* d_ws, size_t ws_size,
                              hipStream_t stream) {
  const float* x = (const float*)d_in[0];
  float* ws = (float*)d_ws;
  float* out = (float*)d_out;

  PrepArgs pa;
  for (int i = 0; i < 39; i++) pa.p[i] = (const float*)d_in[i];
  k_table<<<dim3(20), dim3(256), 0, stream>>>(pa, ws, ws + P_TAB);

  k_mode_mlp<<<dim3(16,16,4), dim3(16,16), 0, stream>>>(x, ws + P_TAB, ws + P_D);

  const float* scw = (const float*)d_in[17];
  const float* scb = (const float*)d_in[18];
  {
    int total = 128*83*21;   // 4 outputs per thread
    k_down<<<dim3((total+255)/256), dim3(256), 0, stream>>>(ws + P_D, ws + P_D1, scw, scb);
  }
  k_down_rest<<<dim3(128), dim3(256), 0, stream>>>(ws + P_D1, ws, scw, scb);

  k_accum<<<dim3(32,32,4), dim3(256), 0, stream>>>(ws, (const float*)d_in[19],
                                                   (const float*)d_in[25], ws + P_SCORE);

  // ft x3 (v6 + XCD-grouped mapping), ping-pong; /5 folded into last pass
  k_ft<<<dim3(4096), dim3(256), 0, stream>>>(ws + P_SCORE, out, ws, 1.f);
  k_ft<<<dim3(4096), dim3(256), 0, stream>>>(out, ws + P_SCORE, ws, 1.f);
  k_ft<<<dim3(4096), dim3(256), 0, stream>>>(ws + P_SCORE, out, ws, 0.2f);
}

// Round 17
// 339.049 us; speedup vs baseline: 1.4107x; 1.0017x over previous
//
#include <hip/hip_runtime.h>
#include <math.h>

#define EPSI 1e-5f

typedef float f32x2 __attribute__((ext_vector_type(2)));

// ---------------- workspace layout (floats) ----------------
#define P_D1 2048                    // 128*83*83 = 881792
#define P_D2 (P_D1 + 128*83*83)
#define P_D3 (P_D2 + 128*28*28)
#define P_D4 (P_D3 + 128*10*10)
#define P_D5 (P_D4 + 128*4*4)
#define P_SCORE (P_D5 + 128*2*2)     // 4*64*256*256 = 16777216 floats
#define P_D  P_SCORE                 // d (4,32,248,248) = 7.87M floats, aliases score head
#define P_TAB (P_SCORE + 8388608)    // 17^3 x 32 MLP table in dead tail of score region

__device__ __forceinline__ float rfl(float x) {
  return __builtin_bit_cast(float, __builtin_amdgcn_readfirstlane(__builtin_bit_cast(int, x)));
}

struct PrepArgs { const float* p[39]; };

// ---------------- prep (in-LDS, per block) + 17^3 -> 32 MLP lookup table ----------------
__global__ __launch_bounds__(256) void k_table(PrepArgs a, float* __restrict__ P,
                                               float* __restrict__ T) {
  __shared__ float Pl[1568];
  int t = threadIdx.x;
  {
    const float *w1=a.p[1],*b1=a.p[2],*w2=a.p[3],*b2=a.p[4],*g1=a.p[5],*bb1=a.p[6],*m1=a.p[7],*v1=a.p[8];
    const float *w3=a.p[9],*b3=a.p[10],*w4=a.p[11],*b4=a.p[12],*g2=a.p[13],*bb2=a.p[14],*m2=a.p[15],*v2=a.p[16];
    for (int i=t;i<96;i+=256){ int o=i/3; float s=g1[o]/sqrtf(v1[o]+EPSI); Pl[i]=w1[i]*w2[o]*s; }
    for (int o=t;o<32;o+=256){ float s=g1[o]/sqrtf(v1[o]+EPSI); Pl[96+o]=(b1[o]*w2[o]+b2[o]-m1[o])*s+bb1[o]; }
    for (int i=t;i<1024;i+=256){ int o2=i/32; float s=g2[o2]/sqrtf(v2[o2]+EPSI); Pl[128+i]=w3[i]*w4[o2]*s; }
    for (int o=t;o<32;o+=256){ float s=g2[o]/sqrtf(v2[o]+EPSI); Pl[1152+o]=(b3[o]*w4[o]+b4[o]-m2[o])*s+bb2[o]; }
    const float *iag=a.p[21],*iab=a.p[22],*iam=a.p[23],*iav=a.p[24],*iabias=a.p[20];
    for (int c=t;c<32;c+=256){ float s=iag[c]/sqrtf(iav[c]+EPSI); Pl[1184+c]=s; Pl[1216+c]=(iabias[0]-iam[c])*s+iab[c]; }
    const float *ibg=a.p[27],*ibb=a.p[28],*ibm=a.p[29],*ibv=a.p[30],*ibbias=a.p[26];
    for (int c=t;c<32;c+=256){ float s=ibg[c]/sqrtf(ibv[c]+EPSI); Pl[1248+c]=s; Pl[1280+c]=(ibbias[0]-ibm[c])*s+ibb[c]; }
    const float *f1g=a.p[31],*f1b=a.p[32],*f1m=a.p[33],*f1v=a.p[34];
    for (int c=t;c<64;c+=256){ float s=f1g[c]/sqrtf(f1v[c]+EPSI); Pl[1312+c]=s; Pl[1376+c]=f1b[c]-f1m[c]*s; }
    const float *f2g=a.p[35],*f2b=a.p[36],*f2m=a.p[37],*f2v=a.p[38];
    for (int c=t;c<64;c+=256){ float s=f2g[c]/sqrtf(f2v[c]+EPSI); Pl[1440+c]=s; Pl[1504+c]=f2b[c]-f2m[c]*s; }
  }
  __syncthreads();
  if (blockIdx.x == 0) {
    for (int i = t; i < 1568; i += 256) P[i] = Pl[i];
  }
  int idx = blockIdx.x*256 + t;
  if (idx >= 4913) return;
  int m0 = idx/289; int rem = idx - m0*289; int m1 = rem/17; int m2 = rem - m1*17;
  float md0 = (float)m0*0.0625f, md1 = (float)m1*0.0625f, md2 = (float)m2*0.0625f;
  const float* A1 = Pl;           const float* C1 = Pl + 96;
  const float* A2 = Pl + 128;     const float* C2 = Pl + 1152;
  float h[32];
  #pragma unroll
  for (int o = 0; o < 32; o++) {
    float v = C1[o] + A1[o*3]*md0 + A1[o*3+1]*md1 + A1[o*3+2]*md2;
    h[o] = (v >= 0.f) ? v : 0.01f*v;
  }
  float* tp = T + (size_t)idx*32;
  #pragma unroll
  for (int o2 = 0; o2 < 32; o2++) {
    float acc = C2[o2];
    #pragma unroll
    for (int o = 0; o < 32; o++) acc += A2[o2*32+o]*h[o];
    tp[o2] = (acc >= 0.f) ? acc : 0.01f*acc;
  }
}

// ---------------- quantize + mode-pool(11,1,1) via separable column-histograms + table ----------
__global__ __launch_bounds__(256) void k_mode_mlp(const float* __restrict__ x,
                                                 const float* __restrict__ T,
                                                 float* __restrict__ dout) {
  __shared__ int qs[3*676];          // 8.1 KB
  __shared__ unsigned CH[3*1326];    // 15.9 KB; plane w: w*1326 + ch*442 + cx*17 + oy
  int lx = threadIdx.x, ly = threadIdx.y;
  int tid = ly*16 + lx;
  int tx0 = blockIdx.x*16, ty0 = blockIdx.y*16;
  int b = blockIdx.z;
  for (int k = tid; k < 3*676; k += 256) {
    int cch = k/676; int rem = k - cch*676; int r = rem/26; int cc = rem - r*26;
    int gy = ty0 + r - 1, gx = tx0 + cc - 1;
    int q = 0;
    if ((unsigned)gy < 256u && (unsigned)gx < 256u) {
      float v = x[((size_t)(b*3+cch)*256 + gy)*256 + gx];
      q = (int)rintf(v*255.0f/16.0f);
      q = q < 0 ? 0 : (q > 16 ? 16 : q);
    }
    qs[k] = q;
  }
  __syncthreads();

  if (tid < 156) {
    int half = tid & 1; int rem = tid >> 1;
    int cx = rem % 26; int ch = rem / 26;
    const int* qp = &qs[ch*676 + cx];
    int oy0 = half*8;
    unsigned w0=0, w1=0, w2=0;
    #pragma unroll 1
    for (int r = oy0; r < oy0+11; r++) {
      int q = qp[r*26];
      unsigned inc = 1u << ((q & 7) << 2);
      int sel = q >> 3;
      w0 += (sel==0)?inc:0u; w1 += (sel==1)?inc:0u; w2 += (sel==2)?inc:0u;
    }
    unsigned base = (unsigned)(ch*442 + cx*17 + oy0);
    CH[base] = w0; CH[1326+base] = w1; CH[2652+base] = w2;
    #pragma unroll 1
    for (int i = 1; i < 8; i++) {
      int qr = qp[(oy0+i-1)*26];
      unsigned incr = 1u << ((qr & 7) << 2);
      int selr = qr >> 3;
      w0 -= (selr==0)?incr:0u; w1 -= (selr==1)?incr:0u; w2 -= (selr==2)?incr:0u;
      int qa = qp[(oy0+i+10)*26];
      unsigned inca = 1u << ((qa & 7) << 2);
      int sela = qa >> 3;
      w0 += (sela==0)?inca:0u; w1 += (sela==1)?inca:0u; w2 += (sela==2)?inca:0u;
      CH[base+i] = w0; CH[1326+base+i] = w1; CH[2652+base+i] = w2;
    }
  }
  __syncthreads();

  int oi = ty0 + ly, oj = tx0 + lx;
  if (oi >= 248 || oj >= 248) return;

  int mode[3];
  #pragma unroll
  for (int ch = 0; ch < 3; ch++) {
    unsigned a0=0,a1=0,a2=0,a3=0,a4=0;
    unsigned base = (unsigned)(ch*442 + lx*17 + ly);
    #pragma unroll
    for (int d = 0; d < 11; d++) {
      unsigned r0 = CH[base + d*17];
      unsigned r1 = CH[1326 + base + d*17];
      unsigned r2 = CH[2652 + base + d*17];
      a0 += r0 & 0x0F0F0F0Fu;
      a1 += (r0 >> 4) & 0x0F0F0F0Fu;
      a2 += r1 & 0x0F0F0F0Fu;
      a3 += (r1 >> 4) & 0x0F0F0F0Fu;
      a4 += r2;
    }
    // argmax via order-preserving key: equal counts -> larger (31-level) wins -> smallest level
    unsigned best = 0u;
    #define KEY(l, wreg) { unsigned cnt = ((wreg) >> ((((l)>>1)&3)*8)) & 255u; \
                           unsigned key = cnt*32u + (31u - (unsigned)(l)); \
                           best = (key > best) ? key : best; }
    KEY(0,a0) KEY(1,a1) KEY(2,a0) KEY(3,a1) KEY(4,a0) KEY(5,a1) KEY(6,a0) KEY(7,a1)
    KEY(8,a2) KEY(9,a3) KEY(10,a2) KEY(11,a3) KEY(12,a2) KEY(13,a3) KEY(14,a2) KEY(15,a3)
    { unsigned cnt = a4 & 255u; unsigned key = cnt*32u + 15u; best = (key > best) ? key : best; }
    #undef KEY
    mode[ch] = 31 - (int)(best & 31u);
  }
  int idx = (mode[0]*17 + mode[1])*17 + mode[2];
  const float* tp = T + (size_t)idx*32;
  size_t ob = ((size_t)(b*32)*248 + oi)*248 + oj;
  #pragma unroll
  for (int o2 = 0; o2 < 32; o2 += 4) {
    float4 v = *(const float4*)(tp + o2);
    dout[ob + (size_t)o2*61504]     = v.x;
    dout[ob + (size_t)(o2+1)*61504] = v.y;
    dout[ob + (size_t)(o2+2)*61504] = v.z;
    dout[ob + (size_t)(o2+3)*61504] = v.w;
  }
}

// ---------------- shared 3x3 conv, stride 3, pad 1 (248 -> 83), 4 outputs/thread ----------------
__global__ void k_down(const float* __restrict__ in, float* __restrict__ out,
                       const float* __restrict__ scw, const float* __restrict__ scb) {
  const int Hin = 248, total = 128*83*21;
  int idx = blockIdx.x*256 + threadIdx.x;
  if (idx >= total) return;
  float w[9];
  #pragma unroll
  for (int i = 0; i < 9; i++) w[i] = rfl(scw[i]);
  float bias = rfl(scb[0]);
  int t = idx % 21; int r2 = idx / 21; int i = r2 % 83; int p = r2 / 83;
  const float* base = in + (size_t)p*Hin*Hin;
  float s0 = bias, s1 = bias, s2 = bias, s3 = bias;
  #pragma unroll
  for (int u = 0; u < 3; u++) {
    int r = 3*i - 1 + u;
    bool rok = ((unsigned)r < 248u);
    const float* rp = base + (size_t)r*Hin;
    float f[16];
    #pragma unroll
    for (int s4 = 0; s4 < 4; s4++) {
      int c0 = 12*t - 4 + 4*s4;
      float4 v = make_float4(0.f,0.f,0.f,0.f);
      if (rok && c0 >= 0 && c0 <= 244) v = *(const float4*)(rp + c0);
      f[s4*4+0] = v.x; f[s4*4+1] = v.y; f[s4*4+2] = v.z; f[s4*4+3] = v.w;
    }
    #pragma unroll
    for (int v = 0; v < 3; v++) {
      float wv = w[u*3+v];
      s0 += f[3+v]*wv;
      s1 += f[6+v]*wv;
      s2 += f[9+v]*wv;
      s3 += f[12+v]*wv;
    }
  }
  float* op = out + (size_t)p*6889 + (size_t)i*83 + 4*t;
  int j0 = 4*t;
  if (j0   < 83) op[0] = s0;
  if (j0+1 < 83) op[1] = s1;
  if (j0+2 < 83) op[2] = s2;
  if (j0+3 < 83) op[3] = s3;
}

// ---------------- merged tail downsamples: 83->28->10->4->2, one block per (b,c) ----------------
__global__ __launch_bounds__(256) void k_down_rest(const float* __restrict__ in, float* __restrict__ ws,
                                                   const float* __restrict__ scw, const float* __restrict__ scb) {
  __shared__ float buf[6889 + 784 + 100 + 16];   // 31.2 KB
  int tid = threadIdx.x; int p = blockIdx.x;     // 128 blocks
  float w[9];
  #pragma unroll
  for (int i = 0; i < 9; i++) w[i] = rfl(scw[i]);
  float bias = rfl(scb[0]);
  const float* src = in + (size_t)p*6889;
  for (int k = tid; k < 6889; k += 256) buf[k] = src[k];
  __syncthreads();
  const int HIN[4] = {83,28,10,4}, HOUT[4] = {28,10,4,2};
  const int OIN[4] = {0, 6889, 6889+784, 6889+784+100};
  const size_t GOFF[4] = {P_D2, P_D3, P_D4, P_D5};
  #pragma unroll
  for (int st = 0; st < 4; st++) {
    const int hin = HIN[st], hout = HOUT[st];
    const float* bi = buf + OIN[st];
    float* bo = buf + OIN[st] + hin*hin;
    float* go = ws + GOFF[st] + (size_t)p*(hout*hout);
    for (int k = tid; k < hout*hout; k += 256) {
      int i = k/hout, j = k - i*hout;
      float s = bias;
      #pragma unroll
      for (int u = 0; u < 3; u++) {
        int r = 3*i - 1 + u;
        if ((unsigned)r < (unsigned)hin) {
          #pragma unroll
          for (int v = 0; v < 3; v++) {
            int cc = 3*j - 1 + v;
            if ((unsigned)cc < (unsigned)hin) s += bi[r*hin + cc]*w[u*3+v];
          }
        }
      }
      bo[k] = s; go[k] = s;
    }
    __syncthreads();
  }
}

// ---------------- pyramid: pk-FMA core + f32x2-PAIRED staging (phases A & B) ----------------
// Staging issue-count ~halved: phase A task = (row, col-pair) -> one div/mod + one
// ds_write_b64 per 2 cols; phase B reads hrow as f32x2 pairs (all even offsets, 8B
// aligned) and writes zt as f32x2. Same LDS / barriers / occupancy as the 82.7 us form.
#define NSP_PACK (83u | (28u<<7) | (10u<<14) | (4u<<21) | (2u<<28))
#define ZROT(r) ((((r)&3) ^ (((r)>>2)&3)) << 3)
__global__ __launch_bounds__(256) void k_accum(const float* __restrict__ ws,
                                               const float* __restrict__ iaw,
                                               const float* __restrict__ ibw,
                                               float* __restrict__ score) {
  __shared__ __align__(16) float hrow[14*96];   // 5.25 KB
  __shared__ __align__(16) float zt[36*96];     // 13.8 KB
  int tid = threadIdx.x;
  int c = blockIdx.y, b = blockIdx.z;
  int tx0 = (blockIdx.x & 3)*64, ty0 = (blockIdx.x >> 2)*32;
  int half = tid >> 7;                         // 0 = branch A, 1 = branch B
  int t2 = tid & 127;
  int lx4 = (t2 & 15)*4, lyt = t2 >> 4;        // 16x8 threads, 4w x 4h px each

  const float* wp = half ? ibw : iaw;
  float w[25];
  #pragma unroll
  for (int i = 0; i < 25; i++) w[i] = rfl(wp[i]);
  float s_ = rfl(ws[1184 + half*64 + c]);
  float C_ = rfl(ws[1216 + half*64 + c]);

  int bzy = tid >> 3;          // 0..31
  int bzx0 = tid & 7;

  float acc[16];
  #pragma unroll
  for (int i = 0; i < 16; i++) acc[i] = 0.f;

  size_t off = P_D1;
  #pragma unroll 1
  for (int lvl = 0; lvl < 5; lvl++) {
    const int n = (int)((NSP_PACK >> (7*lvl)) & 127u);
    const float inv = (float)n * (1.f/256.f);
    float f0 = ((float)(ty0-2)+0.5f)*inv - 0.5f;
    float f1 = ((float)(ty0+33)+0.5f)*inv - 0.5f;
    int yb0 = min(max((int)floorf(f0),0), n-2);
    int yb1 = min(max((int)floorf(f1),0), n-2);
    int rows = yb1 - yb0 + 2;
    const float* dp = ws + off + (size_t)(b*32+c)*(n*n);

    // ---- A: stage x-lerped rows, col-PAIRS (34 pairs/row) ----
    #pragma unroll 1
    for (int k = tid; k < rows*34; k += 256) {
      int r = k/34, cp = k - r*34;
      int zx = 2*cp;
      const float* rowp = dp + (yb0 + r)*n;
      f32x2 h = (f32x2)(0.f);
      #pragma unroll
      for (int e = 0; e < 2; e++) {
        int gx = tx0 + zx + e - 2;
        if ((unsigned)gx < 256u) {
          float f = ((float)gx + 0.5f)*inv - 0.5f;
          float ff = floorf(f);
          int i0 = (int)ff;
          int xb = min(max(i0,0), n-2);
          float wx = (i0 < 0) ? 0.f : (i0 > n-2 ? 1.f : f - ff);
          const float* rp = rowp + xb;
          h[e] = rp[0] + wx*(rp[1] - rp[0]);
        }
      }
      *(f32x2*)&hrow[r*96 + ((r&3)<<3) + zx] = h;
    }
    __syncthreads();

    // ---- B: build unique z tile (y-lerp), f32x2 pairs ----
    {
      int gy = ty0 - 2 + bzy;
      float f = ((float)gy + 0.5f)*inv - 0.5f;
      float ff = floorf(f);
      int i0 = (int)ff;
      int yb = min(max(i0,0), n-2);
      float wy = (i0 < 0) ? 0.f : (i0 > n-2 ? 1.f : f - ff);
      bool vy = ((unsigned)gy < 256u);
      int rel = yb - yb0;
      int ra = rel*96 + ((rel&3)<<3);
      int rb = (rel+1)*96 + (((rel+1)&3)<<3);
      int zr0 = bzy*96 + ZROT(bzy);
      #pragma unroll
      for (int s = 0; s < 5; s++) {
        int zx = 2*bzx0 + 16*s;
        if (zx < 68) {
          f32x2 v = (f32x2)(0.f);
          if (vy) {
            f32x2 a = *(const f32x2*)&hrow[ra + zx];
            f32x2 bb = *(const f32x2*)&hrow[rb + zx];
            v = a + wy*(bb - a);
          }
          *(f32x2*)&zt[zr0 + zx] = v;
        }
      }
      // tail rows 32..35: 4 rows x 34 pairs = 136 tasks (single pass, 136 < 256)
      if (tid < 136) {
        int zy = 32 + tid/34; int cp = tid - (tid/34)*34; int zx = 2*cp;
        int gy2 = ty0 - 2 + zy;
        f32x2 v = (f32x2)(0.f);
        if ((unsigned)gy2 < 256u) {
          float f2 = ((float)gy2 + 0.5f)*inv - 0.5f;
          float ff2 = floorf(f2);
          int i02 = (int)ff2;
          int yb2 = min(max(i02,0), n-2);
          float wy2 = (i02 < 0) ? 0.f : (i02 > n-2 ? 1.f : f2 - ff2);
          int rel2 = yb2 - yb0;
          f32x2 a = *(const f32x2*)&hrow[rel2*96 + ((rel2&3)<<3) + zx];
          f32x2 bb = *(const f32x2*)&hrow[(rel2+1)*96 + (((rel2+1)&3)<<3) + zx];
          v = a + wy2*(bb - a);
        }
        *(f32x2*)&zt[zy*96 + ZROT(zy) + zx] = v;
      }
    }
    __syncthreads();

    // ---- C: conv, branch-split, float2 column-pairs (pk-FMA) ----
    f32x2 cc2[4][2];
    #pragma unroll
    for (int p = 0; p < 4; p++)
      #pragma unroll
      for (int j2 = 0; j2 < 2; j2++) cc2[p][j2] = (f32x2)(0.f);
    #pragma unroll
    for (int zr = 0; zr < 8; zr++) {
      int row = 4*lyt + zr;
      int o = row*96 + ZROT(row) + lx4;
      float4 a0 = *(const float4*)&zt[o];
      float4 a1 = *(const float4*)&zt[o+4];
      float zz[8] = {a0.x,a0.y,a0.z,a0.w,a1.x,a1.y,a1.z,a1.w};
      #pragma unroll
      for (int p = 0; p < 4; p++) {
        int r = zr - p;
        if (r >= 0 && r < 5) {
          #pragma unroll
          for (int v = 0; v < 5; v++) {
            float wv = w[r*5+v];
            cc2[p][0] += (f32x2){zz[v],   zz[v+1]} * wv;
            cc2[p][1] += (f32x2){zz[v+2], zz[v+3]} * wv;
          }
        }
      }
    }
    #pragma unroll
    for (int p = 0; p < 4; p++)
      #pragma unroll
      for (int j2 = 0; j2 < 2; j2++) {
        f32x2 v2 = cc2[p][j2]*s_ + C_;
        #pragma unroll
        for (int e = 0; e < 2; e++) {
          float v = v2[e];
          acc[p*4 + j2*2 + e] += (v >= 0.f) ? v : 0.01f*v;
        }
      }
    off += (size_t)128*n*n;
  }
  int oy = ty0 + 4*lyt, ox = tx0 + lx4;
  size_t base = ((size_t)(b*64 + half*32 + c)*256 + oy)*256 + ox;
  #pragma unroll
  for (int p = 0; p < 4; p++)
    *(float4*)&score[base + (size_t)p*256] = make_float4(acc[p*4],acc[p*4+1],acc[p*4+2],acc[p*4+3]);
}

// ---------------- ft pass v6 + XCD-grouped block mapping (round-14 measured best) ----------------
__global__ __launch_bounds__(256) void k_ft(const float* __restrict__ in,
                                            float* __restrict__ out,
                                            const float* __restrict__ P, float scale) {
  __shared__ __align__(8) float Bf2[8*271*2];  // [(r>>1)*271 + 5+col]*2 + (r&1); 17.3 KB
  int tid = threadIdx.x;         // = column
  int d = blockIdx.x;            // 0..4095
  int qlo = d & 7, rest = d >> 3;
  int xt = rest & 15, qhi = rest >> 4;
  int q = qlo + 8*qhi;           // 0..255 = c + 64*b
  int c = q & 63, b = q >> 6;
  int ty0 = xt * 16;
  float fs1 = rfl(P[1312+c]), fc1 = rfl(P[1376+c]), fs2 = rfl(P[1440+c]), fc2 = rfl(P[1504+c]);
  const float* ip = in + (size_t)(b*64 + c)*65536 + tid;

  // halo zeros: 8 row-pairs x 10 halo cols (idx 0..4 = cols -5..-1, 261..265 = cols 256..260)
  if (tid < 80) {
    int r2 = tid / 10, qq = tid - r2*10;
    int pc = (qq < 5 ? qq : 256 + qq);
    *(f32x2*)&Bf2[(r2*271 + pc)*2] = (f32x2)(0.f);
  }

  float yreg[16];
  float win[11];
  float run = 0.f, prev = 0.f;
  #pragma unroll
  for (int s = 0; s < 26; s++) {
    int gy = ty0 + s - 5;
    float yv = 0.f;
    if ((unsigned)gy < 256u) {
      float t = ip[(size_t)gy*256]*fs1 + fc1;
      t = (t > 0.1f) ? t : 0.7f*t;
      yv = t*fs2 + fc2;
    }
    win[s % 11] = yv;
    run += yv;
    if (s >= 5 && s <= 20) yreg[s-5] = yv;
    if (s >= 10) {
      int r = s - 10;                         // 0..15
      if ((r & 1) == 0) prev = run;
      else *(f32x2*)&Bf2[((r>>1)*271 + 5 + tid)*2] = (f32x2){prev, run};
      run -= win[r % 11];
    }
  }
  __syncthreads();

  const size_t ob = (size_t)(b*64 + c)*65536 + (size_t)ty0*256 + tid;
  #pragma unroll
  for (int r2 = 0; r2 < 8; r2++) {
    const float* bp = &Bf2[(r2*271 + tid)*2];  // window cols tid-5..tid+5 -> pair idx tid..tid+10
    f32x2 s2 = *(const f32x2*)bp;
    #pragma unroll
    for (int dd = 1; dd < 11; dd++) s2 += *(const f32x2*)(bp + 2*dd);
    float y0 = yreg[r2*2], y1 = yreg[r2*2+1];
    float sig0 = 1.f/(1.f + __expf(-(y0 - s2.x*(1.f/121.f))));
    float sig1 = 1.f/(1.f + __expf(-(y1 - s2.y*(1.f/121.f))));
    out[ob + (size_t)(r2*2)*256]   = y0*sig0*scale;
    out[ob + (size_t)(r2*2+1)*256] = y1*sig1*scale;
  }
}

// ---------------- launch ----------------
extern "C" void kernel_launch(void* const* d_in, const int* in_sizes, int n_in,
                              void* d_out, int out_size, void* d_ws, size_t ws_size,
                              hipStream_t stream) {
  const float* x = (const float*)d_in[0];
  float* ws = (float*)d_ws;
  float* out = (float*)d_out;

  PrepArgs pa;
  for (int i = 0; i < 39; i++) pa.p[i] = (const float*)d_in[i];
  k_table<<<dim3(20), dim3(256), 0, stream>>>(pa, ws, ws + P_TAB);

  k_mode_mlp<<<dim3(16,16,4), dim3(16,16), 0, stream>>>(x, ws + P_TAB, ws + P_D);

  const float* scw = (const float*)d_in[17];
  const float* scb = (const float*)d_in[18];
  {
    int total = 128*83*21;   // 4 outputs per thread
    k_down<<<dim3((total+255)/256), dim3(256), 0, stream>>>(ws + P_D, ws + P_D1, scw, scb);
  }
  k_down_rest<<<dim3(128), dim3(256), 0, stream>>>(ws + P_D1, ws, scw, scb);

  k_accum<<<dim3(32,32,4), dim3(256), 0, stream>>>(ws, (const float*)d_in[19],
                                                   (const float*)d_in[25], ws + P_SCORE);

  // ft x3 (v6 + XCD-grouped mapping), ping-pong; /5 folded into last pass
  k_ft<<<dim3(4096), dim3(256), 0, stream>>>(ws + P_SCORE, out, ws, 1.f);
  k_ft<<<dim3(4096), dim3(256), 0, stream>>>(out, ws + P_SCORE, ws, 1.f);
  k_ft<<<dim3(4096), dim3(256), 0, stream>>>(ws + P_SCORE, out, ws, 0.2f);
}